// Round 7
// baseline (143.387 us; speedup 1.0000x reference)
//
#include <hip/hip_runtime.h>
#include <hip/hip_bf16.h>
#include <stdint.h>
#include <stddef.h>

// Problem constants (from reference)
#define IN_F     1024
#define OUT_F    1024
#define BATCH    4096
#define NSPLINE  8            // GRID_SIZE + SPLINE_ORDER
#define KDIM     (IN_F * 9)   // 9216 : plane 0 = silu(x), planes 1..8 = spline basis
#define GRIDPTS  12           // GRID_SIZE + 2*SPLINE_ORDER + 1

typedef __bf16 bf16;
typedef __bf16 bf16x8 __attribute__((ext_vector_type(8)));
typedef float  f32x4  __attribute__((ext_vector_type(4)));

// -------------------------------------------------------------------------
// Kernel 1: build augmented activation matrix A[BATCH][KDIM] in bf16.
// -------------------------------------------------------------------------
__global__ __launch_bounds__(256) void build_A(const float* __restrict__ x,
                                               const float* __restrict__ grid,
                                               bf16* __restrict__ A)
{
    __shared__ float g[GRIDPTS];
    __shared__ float rec[33];   // rec[(k-1)*11 + j] = 1/(g[j+k]-g[j]+1e-8)
    if (threadIdx.x < GRIDPTS) g[threadIdx.x] = grid[threadIdx.x];  // row 0 (rows identical)
    __syncthreads();
    if (threadIdx.x < 33) {
        const int k = threadIdx.x / 11 + 1;
        const int j = threadIdx.x % 11;
        if (j + k <= 11) rec[threadIdx.x] = 1.0f / (g[j + k] - g[j] + 1e-8f);
    }
    __syncthreads();

    const int idx = blockIdx.x * 256 + threadIdx.x;   // b*IN_F + i
    const int b = idx >> 10;
    const int i = idx & 1023;
    const float xv = x[idx];

    float bs[11];
#pragma unroll
    for (int j = 0; j < 11; ++j)
        bs[j] = (xv >= g[j] && xv < g[j + 1]) ? 1.0f : 0.0f;

#pragma unroll
    for (int k = 1; k <= 3; ++k) {
        const float* rk = &rec[(k - 1) * 11];
#pragma unroll
        for (int j = 0; j < 10; ++j) {
            if (j <= 10 - k) {
                bs[j] = (xv - g[j]) * rk[j] * bs[j]
                      + (g[j + k + 1] - xv) * rk[j + 1] * bs[j + 1];
            }
        }
    }

    const float si = xv / (1.0f + __expf(-xv));   // silu

    bf16* rowp = A + (size_t)b * KDIM;
    rowp[i] = (bf16)si;
#pragma unroll
    for (int j = 0; j < NSPLINE; ++j)
        rowp[(size_t)(j + 1) * IN_F + i] = (bf16)bs[j];
}

// -------------------------------------------------------------------------
// Kernel 2: pack weights W[OUT_F][KDIM] in bf16 (scaler fused into spline w).
// -------------------------------------------------------------------------
__global__ __launch_bounds__(256) void pack_W(const float* __restrict__ bw,
                                              const float* __restrict__ sw,
                                              const float* __restrict__ sc,
                                              bf16* __restrict__ W)
{
    const int idx = blockIdx.x * 256 + threadIdx.x;   // o*IN_F + i
    const int i = idx & 1023;
    const float s = sc[idx];

    bf16* rowp = W + (size_t)(idx >> 10) * KDIM;
    rowp[i] = (bf16)bw[idx];

    const float4* swv = (const float4*)(sw + (size_t)idx * NSPLINE);
    const float4 w0 = swv[0];
    const float4 w1 = swv[1];
    rowp[(size_t)1 * IN_F + i] = (bf16)(w0.x * s);
    rowp[(size_t)2 * IN_F + i] = (bf16)(w0.y * s);
    rowp[(size_t)3 * IN_F + i] = (bf16)(w0.z * s);
    rowp[(size_t)4 * IN_F + i] = (bf16)(w0.w * s);
    rowp[(size_t)5 * IN_F + i] = (bf16)(w1.x * s);
    rowp[(size_t)6 * IN_F + i] = (bf16)(w1.y * s);
    rowp[(size_t)7 * IN_F + i] = (bf16)(w1.z * s);
    rowp[(size_t)8 * IN_F + i] = (bf16)(w1.w * s);
}

// -------------------------------------------------------------------------
// Kernel 3: 128x128x64 split-K GEMM, 2 blocks/CU (T1+T2+T4+T5).
//   C_part[z][M][N] = A[M][kslice] * W[N][kslice]^T  (both K-contiguous)
// 512 threads = 8 waves (2M x 4N); per-wave output 64x32 (acc[4][2] f32x4).
// LDS: ring of 8 slots x 8KB; slot = one K-half [128 rows][32 k] bf16,
// T2-swizzled: physical 16-B k-chunk = kc ^ ((row>>1)&3); global source
// pre-permuted per lane (rule #21). 64 KB LDS + ~100 VGPR -> 2 blocks/CU,
// so barrier stalls of one block are absorbed by the co-resident block
// (the lever this round: occupancy, vs round-6's 1 block/CU lockstep).
//
// Per K-tile t (halves h=4t..4t+3 = A-kh0,B-kh0,A-kh1,B-kh1), 2 phases:
//   { 6 ds_read_b128 (this phase's frags); stage 2 halves (lead +6);
//     counted vmcnt(4); s_barrier; lgkmcnt(0); setprio(1); 8 MFMA;
//     setprio(0); s_barrier }
// Cross-wave safety: a slot is read only after a barrier preceded by
// EVERY wave's vmcnt covering it (phase-1 vmcnt(4): issued<=4t+7 ->
// landed<=4t+3, covers phase-2 reads; tile t-1 phase-2 vmcnt(4) covers
// phase-1 reads). Read latency hides under the barrier wait (m201).
// -------------------------------------------------------------------------
#define BM8 128
#define BN8 128
#define BK8 64

#define GLOAD_LDS16(gp, lp)                                                          \
    __builtin_amdgcn_global_load_lds((const __attribute__((address_space(1))) void*)(gp), \
                                     (__attribute__((address_space(3))) void*)(lp), 16, 0, 0)

__global__ __launch_bounds__(512, 4) void gemm8(const bf16* __restrict__ A,
                                                const bf16* __restrict__ B,
                                                float* __restrict__ C,
                                                int kLen)
{
    __shared__ bf16 lds[8 * 4096];   // 8 half-slots x 8 KB = 64 KB

    const int tid  = threadIdx.x;
    const int wave = tid >> 6;
    const int lane = tid & 63;

    // bijective XCD swizzle (gridDim.x % 8 == 0 for all split degrees here)
    const int nwg  = gridDim.x;
    const int q    = nwg >> 3;
    const int wgid = (blockIdx.x & 7) * q + (blockIdx.x >> 3);
    const int nxy  = (BATCH / BM8) * (OUT_F / BN8);   // 32*8 = 256
    const int z    = wgid / nxy;
    const int rem  = wgid - z * nxy;
    const int by   = rem >> 5;           // 0..7  (N tile)
    const int bx   = rem & 31;           // 0..31 (M tile)

    const int bm   = bx * BM8;
    const int bcol = by * BN8;
    const int kBase = z * kLen;
    C += (size_t)z * BATCH * OUT_F;      // partial buffer (z=0 when split=1)

    const int wr = (wave >> 2) * 64;     // 2 M-waves
    const int wc = (wave & 3) * 32;      // 4 N-waves

    f32x4 acc[4][2] = {};

    const int NT   = kLen / BK8;
    const int hmax = 4 * NT;

    // staging geometry: thread covers row tid/4; global k-chunk pre-swizzled
    // so the linear LDS write lands data where the swizzled reader expects.
    const int srow = tid >> 2;           // 0..127
    const int sch  = (((tid & 3) ^ ((tid >> 3) & 3))) * 8;
    const bf16* baseA = A + (size_t)(bm + srow) * KDIM + kBase + sch;
    const bf16* baseB = B + (size_t)(bcol + srow) * KDIM + kBase + sch;
    bf16* ldsw = &lds[wave * 512];       // wave-uniform dest segment (1 KB/wave)

    auto stage = [&](int h) {
        if (h < hmax) {
            const int t   = h >> 2;
            const int th  = h & 3;
            const int kof = t * BK8 + ((th >> 1) ? 32 : 0);
            const bf16* src = (th & 1) ? baseB : baseA;
            GLOAD_LDS16(src + kof, ldsw + (h & 7) * 4096);
        }
    };

    // prologue: stage halves 0..5; vmcnt(4) -> halves 0,1 landed; barrier
    for (int h = 0; h < 6; ++h) stage(h);
    asm volatile("s_waitcnt vmcnt(4)" ::: "memory");
    __builtin_amdgcn_s_barrier();

    const int rowk = lane & 15;
    const int kc   = lane >> 4;          // logical 8-elem k-chunk 0..3
    // (row>>1)&3 == (rowk>>1)&3 for all rows we touch (wr,wc,m*16 ≡ 0 mod 8)
    const int kxor = (kc ^ ((rowk >> 1) & 3)) * 8;

#define LDSFRAG(slot, row) (*(const bf16x8*)&lds[(slot) * 4096 + (row) * 32 + kxor])

    for (int t = 0; t < NT; ++t) {
        const int h0  = 4 * t;
        const int sA0 = (h0 + 0) & 7, sB0 = (h0 + 1) & 7;
        const int sA1 = (h0 + 2) & 7, sB1 = (h0 + 3) & 7;
        bf16x8 a[4], b[2];

        // ---- phase 1: kh0 ----
#pragma unroll
        for (int m = 0; m < 4; ++m) a[m] = LDSFRAG(sA0, wr + m * 16 + rowk);
#pragma unroll
        for (int n = 0; n < 2; ++n) b[n] = LDSFRAG(sB0, wc + n * 16 + rowk);
        stage(h0 + 6);
        stage(h0 + 7);
        if (t < NT - 1) asm volatile("s_waitcnt vmcnt(4)" ::: "memory");
        __builtin_amdgcn_s_barrier();
        asm volatile("s_waitcnt lgkmcnt(0)" ::: "memory");
        __builtin_amdgcn_sched_barrier(0);
        __builtin_amdgcn_s_setprio(1);
#pragma unroll
        for (int m = 0; m < 4; ++m)
#pragma unroll
            for (int n = 0; n < 2; ++n)
                acc[m][n] = __builtin_amdgcn_mfma_f32_16x16x32_bf16(a[m], b[n], acc[m][n], 0, 0, 0);
        __builtin_amdgcn_s_setprio(0);
        __builtin_amdgcn_s_barrier();

        // ---- phase 2: kh1 ----
#pragma unroll
        for (int m = 0; m < 4; ++m) a[m] = LDSFRAG(sA1, wr + m * 16 + rowk);
#pragma unroll
        for (int n = 0; n < 2; ++n) b[n] = LDSFRAG(sB1, wc + n * 16 + rowk);
        stage(h0 + 8);
        stage(h0 + 9);
        if (t < NT - 2)       asm volatile("s_waitcnt vmcnt(4)" ::: "memory");
        else if (t == NT - 2) asm volatile("s_waitcnt vmcnt(0)" ::: "memory");
        __builtin_amdgcn_s_barrier();
        asm volatile("s_waitcnt lgkmcnt(0)" ::: "memory");
        __builtin_amdgcn_sched_barrier(0);
        __builtin_amdgcn_s_setprio(1);
#pragma unroll
        for (int m = 0; m < 4; ++m)
#pragma unroll
            for (int n = 0; n < 2; ++n)
                acc[m][n] = __builtin_amdgcn_mfma_f32_16x16x32_bf16(a[m], b[n], acc[m][n], 0, 0, 0);
        __builtin_amdgcn_s_setprio(0);
        __builtin_amdgcn_s_barrier();
    }
#undef LDSFRAG

    // epilogue: C/D layout col = lane&15, row = (lane>>4)*4 + r
    const int ccol = lane & 15;
    const int crow = (lane >> 4) * 4;
#pragma unroll
    for (int mf = 0; mf < 4; ++mf) {
#pragma unroll
        for (int nf = 0; nf < 2; ++nf) {
            float* cp = C + (size_t)(bm + wr + mf * 16 + crow) * OUT_F + (bcol + wc + nf * 16 + ccol);
#pragma unroll
            for (int r = 0; r < 4; ++r)
                cp[(size_t)r * OUT_F] = acc[mf][nf][r];
        }
    }
}

// -------------------------------------------------------------------------
// Kernel 4: sum nPart partial C buffers into out (float4-vectorized).
// -------------------------------------------------------------------------
__global__ __launch_bounds__(256) void reduce_partials(const float4* __restrict__ P,
                                                       float4* __restrict__ out,
                                                       int nPart, int n4)
{
    const int stride = gridDim.x * 256;
    for (int i = blockIdx.x * 256 + threadIdx.x; i < n4; i += stride) {
        float4 s = P[i];
        for (int p = 1; p < nPart; ++p) {
            const float4 q = P[(size_t)p * n4 + i];
            s.x += q.x; s.y += q.y; s.z += q.z; s.w += q.w;
        }
        out[i] = s;
    }
}

// -------------------------------------------------------------------------
extern "C" void kernel_launch(void* const* d_in, const int* in_sizes, int n_in,
                              void* d_out, int out_size, void* d_ws, size_t ws_size,
                              hipStream_t stream)
{
    const float* x  = (const float*)d_in[0];   // (4096,1024)
    const float* bw = (const float*)d_in[1];   // (1024,1024)
    const float* sw = (const float*)d_in[2];   // (1024,1024,8)
    const float* sc = (const float*)d_in[3];   // (1024,1024)
    const float* gr = (const float*)d_in[4];   // (1024,12) all rows equal
    float* out = (float*)d_out;                // (4096,1024)

    bf16* A = (bf16*)d_ws;                          // 4096*9216*2 = 75.5 MB
    bf16* W = A + (size_t)BATCH * KDIM;             // 1024*9216*2 = 18.9 MB
    float* parts = (float*)(W + (size_t)OUT_F * KDIM);

    const size_t baseBytes = ((size_t)BATCH + OUT_F) * KDIM * sizeof(bf16);
    const size_t cBytes    = (size_t)BATCH * OUT_F * sizeof(float);

    // split-K=2: grid 512 blocks = 2 blocks/CU (the occupancy design point)
    int split = 1;
    if (ws_size >= baseBytes + 2 * cBytes) split = 2;

    build_A<<<(BATCH * IN_F) / 256, 256, 0, stream>>>(x, gr, A);
    pack_W<<<(OUT_F * IN_F) / 256, 256, 0, stream>>>(bw, sw, sc, W);

    const int nblk = (BATCH / BM8) * (OUT_F / BN8) * split;   // 256*split
    float* gemmOut = (split > 1) ? parts : out;
    gemm8<<<nblk, 512, 0, stream>>>(A, W, gemmOut, KDIM / split);

    if (split > 1) {
        const int n4 = BATCH * OUT_F / 4;
        reduce_partials<<<2048, 256, 0, stream>>>((const float4*)parts, (float4*)out,
                                                  split, n4);
    }
}

// Round 8
// 127.789 us; speedup vs baseline: 1.1221x; 1.1221x over previous
//
#include <hip/hip_runtime.h>
#include <hip/hip_bf16.h>
#include <stdint.h>
#include <stddef.h>

// Problem constants (from reference)
#define IN_F     1024
#define OUT_F    1024
#define BATCH    4096
#define NSPLINE  8            // GRID_SIZE + SPLINE_ORDER
#define KDIM     (IN_F * 9)   // 9216 : plane 0 = silu(x), planes 1..8 = spline basis
#define GRIDPTS  12           // GRID_SIZE + 2*SPLINE_ORDER + 1

typedef __bf16 bf16;
typedef __bf16 bf16x8 __attribute__((ext_vector_type(8)));
typedef float  f32x16 __attribute__((ext_vector_type(16)));

// -------------------------------------------------------------------------
// Kernel 1: build augmented activation matrix A[BATCH][KDIM] in bf16.
// -------------------------------------------------------------------------
__global__ __launch_bounds__(256) void build_A(const float* __restrict__ x,
                                               const float* __restrict__ grid,
                                               bf16* __restrict__ A)
{
    __shared__ float g[GRIDPTS];
    __shared__ float rec[33];   // rec[(k-1)*11 + j] = 1/(g[j+k]-g[j]+1e-8)
    if (threadIdx.x < GRIDPTS) g[threadIdx.x] = grid[threadIdx.x];  // row 0 (rows identical)
    __syncthreads();
    if (threadIdx.x < 33) {
        const int k = threadIdx.x / 11 + 1;
        const int j = threadIdx.x % 11;
        if (j + k <= 11) rec[threadIdx.x] = 1.0f / (g[j + k] - g[j] + 1e-8f);
    }
    __syncthreads();

    const int idx = blockIdx.x * 256 + threadIdx.x;   // b*IN_F + i
    const int b = idx >> 10;
    const int i = idx & 1023;
    const float xv = x[idx];

    float bs[11];
#pragma unroll
    for (int j = 0; j < 11; ++j)
        bs[j] = (xv >= g[j] && xv < g[j + 1]) ? 1.0f : 0.0f;

#pragma unroll
    for (int k = 1; k <= 3; ++k) {
        const float* rk = &rec[(k - 1) * 11];
#pragma unroll
        for (int j = 0; j < 10; ++j) {
            if (j <= 10 - k) {
                bs[j] = (xv - g[j]) * rk[j] * bs[j]
                      + (g[j + k + 1] - xv) * rk[j + 1] * bs[j + 1];
            }
        }
    }

    const float si = xv / (1.0f + __expf(-xv));   // silu

    bf16* rowp = A + (size_t)b * KDIM;
    rowp[i] = (bf16)si;
#pragma unroll
    for (int j = 0; j < NSPLINE; ++j)
        rowp[(size_t)(j + 1) * IN_F + i] = (bf16)bs[j];
}

// -------------------------------------------------------------------------
// Kernel 2: pack weights W[OUT_F][KDIM] in bf16 (scaler fused into spline w).
// -------------------------------------------------------------------------
__global__ __launch_bounds__(256) void pack_W(const float* __restrict__ bw,
                                              const float* __restrict__ sw,
                                              const float* __restrict__ sc,
                                              bf16* __restrict__ W)
{
    const int idx = blockIdx.x * 256 + threadIdx.x;   // o*IN_F + i
    const int i = idx & 1023;
    const float s = sc[idx];

    bf16* rowp = W + (size_t)(idx >> 10) * KDIM;
    rowp[i] = (bf16)bw[idx];

    const float4* swv = (const float4*)(sw + (size_t)idx * NSPLINE);
    const float4 w0 = swv[0];
    const float4 w1 = swv[1];
    rowp[(size_t)1 * IN_F + i] = (bf16)(w0.x * s);
    rowp[(size_t)2 * IN_F + i] = (bf16)(w0.y * s);
    rowp[(size_t)3 * IN_F + i] = (bf16)(w0.z * s);
    rowp[(size_t)4 * IN_F + i] = (bf16)(w0.w * s);
    rowp[(size_t)5 * IN_F + i] = (bf16)(w1.x * s);
    rowp[(size_t)6 * IN_F + i] = (bf16)(w1.y * s);
    rowp[(size_t)7 * IN_F + i] = (bf16)(w1.z * s);
    rowp[(size_t)8 * IN_F + i] = (bf16)(w1.w * s);
}

// -------------------------------------------------------------------------
// Kernel 3: 256x256x64 split-K GEMM with 32x32x16 MFMA (T1+T2+T4+T5).
//   C_part[z][M][N] = A[M][kslice] * W[N][kslice]^T  (both K-contiguous)
// 512 threads = 8 waves (2M x 4N); per-wave output 128x64 = 4x2 frags of
// 32x32 (acc[4][2] f32x16). LDS: ring of 8 slots x 16KB; slot = one K-half
// [256 rows][32 k] bf16.
//
// T2 swizzle (same as r4/r6): physical 16-B k-chunk = c ^ ((row>>1)&3);
// global source pre-permuted per lane (rule #21: both-sides-or-neither).
// For the 32x32 read pattern (32 consecutive rows per half-wave at one
// chunk) this gives exactly 8 dwords/bank per ds_read_b128 = conflict-free.
//
// Phase structure (race-free rework of r6): per K-tile t, 4 phases
// (k-steps of 16). Each phase:
//   { stage 1 half (2 gload_lds, lead +6); [P3: counted vmcnt]; s_barrier;
//     prefetch NEXT phase's 6 ds_read_b128; sched_barrier; setprio(1);
//     8 x mfma_32x32x16 (this phase's frags, read last phase); setprio(0) }
// Every cross-wave slot read now happens after a barrier that followed all
// waves' covering vmcnt (P3 vmcnt(4) -> halves <= h0+7 landed; tile-start
// guarantee covers all 4 in-tile halves). Prefetch latency hides under the
// MFMA block; the compiler emits counted lgkmcnt for the consumed frags.
// -------------------------------------------------------------------------
#define BM8 256
#define BN8 256
#define BK8 64

#define GLOAD_LDS16(gp, lp)                                                          \
    __builtin_amdgcn_global_load_lds((const __attribute__((address_space(1))) void*)(gp), \
                                     (__attribute__((address_space(3))) void*)(lp), 16, 0, 0)

__global__ __launch_bounds__(512, 2) void gemm8(const bf16* __restrict__ A,
                                                const bf16* __restrict__ B,
                                                float* __restrict__ C,
                                                int kLen)
{
    __shared__ bf16 lds[8 * 8192];   // 8 half-slots x 16 KB = 128 KB

    const int tid  = threadIdx.x;
    const int wave = tid >> 6;
    const int lane = tid & 63;

    // bijective XCD swizzle (gridDim.x % 8 == 0 for all split degrees here)
    const int nwg  = gridDim.x;
    const int q    = nwg >> 3;
    const int wgid = (blockIdx.x & 7) * q + (blockIdx.x >> 3);
    const int nxy  = (BATCH / BM8) * (OUT_F / BN8);   // 16*4 = 64
    const int z    = wgid / nxy;
    const int rem  = wgid - z * nxy;
    const int by   = rem >> 4;           // 0..3
    const int bx   = rem & 15;           // 0..15

    const int bm   = bx * BM8;
    const int bcol = by * BN8;
    const int kBase = z * kLen;
    C += (size_t)z * BATCH * OUT_F;      // partial buffer (z=0 when split=1)

    const int wr = (wave >> 2) * 128;    // 2 M-waves
    const int wc = (wave & 3) * 64;      // 4 N-waves

    f32x16 acc[4][2] = {};

    const int NT   = kLen / BK8;
    const int hmax = 4 * NT;

    // staging geometry: thread covers rows tid/4 and tid/4+128 of each half;
    // global k-chunk pre-swizzled so the linear LDS write lands data where
    // the swizzled reader expects.
    const int srow = tid >> 2;           // 0..127
    const int sch  = (((tid & 3) ^ ((tid >> 3) & 3))) * 8;
    const bf16* baseA = A + (size_t)(bm + srow) * KDIM + kBase + sch;
    const bf16* baseB = B + (size_t)(bcol + srow) * KDIM + kBase + sch;
    const size_t rstep = (size_t)128 * KDIM;
    bf16* ldsw = &lds[wave * 512];       // wave-uniform dest segment

    auto stage = [&](int h) {
        if (h < hmax) {
            const int t   = h >> 2;
            const int th  = h & 3;
            const int kof = t * BK8 + ((th >> 1) ? 32 : 0);
            const bf16* src = (th & 1) ? baseB : baseA;
            bf16* l0 = ldsw + (h & 7) * 8192;
            GLOAD_LDS16(src + kof, l0);
            GLOAD_LDS16(src + kof + rstep, l0 + 4096);
        }
    };

    // prologue: stage halves 0..5; vmcnt(4) -> halves 0..3 landed; barrier
    for (int h = 0; h < 6; ++h) stage(h);
    asm volatile("s_waitcnt vmcnt(4)" ::: "memory");
    __builtin_amdgcn_s_barrier();

    // 32x32x16 fragment addressing: row = base + (lane&31),
    // k-chunk (16B) = 2*(step&1) + (lane>>5), swizzled by rsw = (row>>1)&3
    // (= (lane>>1)&3 since all row bases are multiples of 32).
    const int l31  = lane & 31;
    const int rsw  = (lane >> 1) & 3;
    const int offE = (((lane >> 5) + 0) ^ rsw) * 8;   // even k-step chunks {0,1}
    const int offO = (((lane >> 5) + 2) ^ rsw) * 8;   // odd  k-step chunks {2,3}

#define LDSFRAG(slot, row, off) (*(const bf16x8*)&lds[(slot) * 8192 + (row) * 32 + (off)])

    bf16x8 a[4], b[2], a2[4], b2[2];
    // pre-read: tile 0, k-step 0 (slots 0 = A-kh0, 1 = B-kh0, even chunks)
#pragma unroll
    for (int m = 0; m < 4; ++m) a[m] = LDSFRAG(0, wr + m * 32 + l31, offE);
#pragma unroll
    for (int n = 0; n < 2; ++n) b[n] = LDSFRAG(1, wc + n * 32 + l31, offE);

    for (int t = 0; t < NT; ++t) {
        const int h0  = 4 * t;
        const int sA0 = (h0 + 0) & 7, sB0 = (h0 + 1) & 7;
        const int sA1 = (h0 + 2) & 7, sB1 = (h0 + 3) & 7;

        // ---- phase 0: MFMA k-step 0 (a,b); prefetch step 1 (kh0, odd) ----
        stage(h0 + 6);
        __builtin_amdgcn_s_barrier();
#pragma unroll
        for (int m = 0; m < 4; ++m) a2[m] = LDSFRAG(sA0, wr + m * 32 + l31, offO);
#pragma unroll
        for (int n = 0; n < 2; ++n) b2[n] = LDSFRAG(sB0, wc + n * 32 + l31, offO);
        __builtin_amdgcn_sched_barrier(0);
        __builtin_amdgcn_s_setprio(1);
#pragma unroll
        for (int m = 0; m < 4; ++m)
#pragma unroll
            for (int n = 0; n < 2; ++n)
                acc[m][n] = __builtin_amdgcn_mfma_f32_32x32x16_bf16(a[m], b[n], acc[m][n], 0, 0, 0);
        __builtin_amdgcn_s_setprio(0);

        // ---- phase 1: MFMA k-step 1 (a2,b2); prefetch step 2 (kh1, even) ----
        stage(h0 + 7);
        __builtin_amdgcn_s_barrier();
#pragma unroll
        for (int m = 0; m < 4; ++m) a[m] = LDSFRAG(sA1, wr + m * 32 + l31, offE);
#pragma unroll
        for (int n = 0; n < 2; ++n) b[n] = LDSFRAG(sB1, wc + n * 32 + l31, offE);
        __builtin_amdgcn_sched_barrier(0);
        __builtin_amdgcn_s_setprio(1);
#pragma unroll
        for (int m = 0; m < 4; ++m)
#pragma unroll
            for (int n = 0; n < 2; ++n)
                acc[m][n] = __builtin_amdgcn_mfma_f32_32x32x16_bf16(a2[m], b2[n], acc[m][n], 0, 0, 0);
        __builtin_amdgcn_s_setprio(0);

        // ---- phase 2: MFMA k-step 2 (a,b); prefetch step 3 (kh1, odd) ----
        stage(h0 + 8);
        __builtin_amdgcn_s_barrier();
#pragma unroll
        for (int m = 0; m < 4; ++m) a2[m] = LDSFRAG(sA1, wr + m * 32 + l31, offO);
#pragma unroll
        for (int n = 0; n < 2; ++n) b2[n] = LDSFRAG(sB1, wc + n * 32 + l31, offO);
        __builtin_amdgcn_sched_barrier(0);
        __builtin_amdgcn_s_setprio(1);
#pragma unroll
        for (int m = 0; m < 4; ++m)
#pragma unroll
            for (int n = 0; n < 2; ++n)
                acc[m][n] = __builtin_amdgcn_mfma_f32_32x32x16_bf16(a[m], b[n], acc[m][n], 0, 0, 0);
        __builtin_amdgcn_s_setprio(0);

        // ---- phase 3: MFMA k-step 3 (a2,b2); vmcnt; barrier; prefetch next
        //      tile's k-step 0 (covered: all waves' vmcnt precedes barrier) --
        stage(h0 + 9);
        if (t < NT - 2)       asm volatile("s_waitcnt vmcnt(4)" ::: "memory");
        else if (t == NT - 2) asm volatile("s_waitcnt vmcnt(0)" ::: "memory");
        __builtin_amdgcn_s_barrier();
        if (t + 1 < NT) {
            const int nA0 = (h0 + 4) & 7, nB0 = (h0 + 5) & 7;
#pragma unroll
            for (int m = 0; m < 4; ++m) a[m] = LDSFRAG(nA0, wr + m * 32 + l31, offE);
#pragma unroll
            for (int n = 0; n < 2; ++n) b[n] = LDSFRAG(nB0, wc + n * 32 + l31, offE);
        }
        __builtin_amdgcn_sched_barrier(0);
        __builtin_amdgcn_s_setprio(1);
#pragma unroll
        for (int m = 0; m < 4; ++m)
#pragma unroll
            for (int n = 0; n < 2; ++n)
                acc[m][n] = __builtin_amdgcn_mfma_f32_32x32x16_bf16(a2[m], b2[n], acc[m][n], 0, 0, 0);
        __builtin_amdgcn_s_setprio(0);
    }
#undef LDSFRAG

    // epilogue: 32x32 C/D layout col = lane&31, row = (reg&3)+8*(reg>>2)+4*(lane>>5)
    const int ccol = l31;
    const int rhi  = 4 * (lane >> 5);
#pragma unroll
    for (int mf = 0; mf < 4; ++mf) {
#pragma unroll
        for (int nf = 0; nf < 2; ++nf) {
            float* cp = C + (size_t)(bm + wr + mf * 32 + rhi) * OUT_F + (bcol + wc + nf * 32 + ccol);
#pragma unroll
            for (int reg = 0; reg < 16; ++reg) {
                const int rl = (reg & 3) + 8 * (reg >> 2);
                cp[(size_t)rl * OUT_F] = acc[mf][nf][reg];
            }
        }
    }
}

// -------------------------------------------------------------------------
// Kernel 4: sum nPart partial C buffers into out (float4-vectorized).
// -------------------------------------------------------------------------
__global__ __launch_bounds__(256) void reduce_partials(const float4* __restrict__ P,
                                                       float4* __restrict__ out,
                                                       int nPart, int n4)
{
    const int stride = gridDim.x * 256;
    for (int i = blockIdx.x * 256 + threadIdx.x; i < n4; i += stride) {
        float4 s = P[i];
        for (int p = 1; p < nPart; ++p) {
            const float4 q = P[(size_t)p * n4 + i];
            s.x += q.x; s.y += q.y; s.z += q.z; s.w += q.w;
        }
        out[i] = s;
    }
}

// -------------------------------------------------------------------------
extern "C" void kernel_launch(void* const* d_in, const int* in_sizes, int n_in,
                              void* d_out, int out_size, void* d_ws, size_t ws_size,
                              hipStream_t stream)
{
    const float* x  = (const float*)d_in[0];   // (4096,1024)
    const float* bw = (const float*)d_in[1];   // (1024,1024)
    const float* sw = (const float*)d_in[2];   // (1024,1024,8)
    const float* sc = (const float*)d_in[3];   // (1024,1024)
    const float* gr = (const float*)d_in[4];   // (1024,12) all rows equal
    float* out = (float*)d_out;                // (4096,1024)

    bf16* A = (bf16*)d_ws;                          // 4096*9216*2 = 75.5 MB
    bf16* W = A + (size_t)BATCH * KDIM;             // 1024*9216*2 = 18.9 MB
    float* parts = (float*)(W + (size_t)OUT_F * KDIM);

    const size_t baseBytes = ((size_t)BATCH + OUT_F) * KDIM * sizeof(bf16);
    const size_t cBytes    = (size_t)BATCH * OUT_F * sizeof(float);

    // split-K degree, gated on workspace size (ws_size fixed -> deterministic)
    int split = 1;
    if (ws_size >= baseBytes + 4 * cBytes)      split = 4;
    else if (ws_size >= baseBytes + 2 * cBytes) split = 2;

    build_A<<<(BATCH * IN_F) / 256, 256, 0, stream>>>(x, gr, A);
    pack_W<<<(OUT_F * IN_F) / 256, 256, 0, stream>>>(bw, sw, sc, W);

    const int nblk = (BATCH / BM8) * (OUT_F / BN8) * split;   // 64*split
    float* gemmOut = (split > 1) ? parts : out;
    gemm8<<<nblk, 512, 0, stream>>>(A, W, gemmOut, KDIM / split);

    if (split > 1) {
        const int n4 = BATCH * OUT_F / 4;
        reduce_partials<<<2048, 256, 0, stream>>>((const float4*)parts, (float4*)out,
                                                  split, n4);
    }
}